// Round 2
// 95.840 us; speedup vs baseline: 1.0480x; 1.0480x over previous
//
#include <hip/hip_runtime.h>
#include <math.h>

#define B_SZ 2048
#define R_SZ 64
#define QT 8                    // q rows per kde block
#define KDE_BLOCKS (B_SZ / QT)  // 256 blocks * 16 waves -> 1 block/CU

#define B_POW_NEG02 0.217637640824031f   // 2048^-0.2 = 2^-2.2
#define SQRT_2PI 2.5066282746310002f
#define LOG2E 1.44269504088896340736f

// native v_exp_f32 (exp2)
extern "C" __device__ float __ocml_native_exp2_f32(float);

typedef __attribute__((ext_vector_type(2))) float f32x2;  // -> v_pk_* f32 ops

// ---------------------------------------------------------------------------
// ws layout (floats):
//   [0:256)     qsums   = per-quarter column sums   (4 x 64)
//   [256:512)   qsums2  = per-quarter column sumsq  (4 x 64)
//   [640]       ent_acc   (own 128B line)
//   [672]       done_cnt  (int, own line)
//   [1024:1024+16384)  gram4 = Gram quarter-partials (64 rows x 4 qtr x 64)
// Everything is write-before-read across the two kernels; no zero-init of
// poisoned ws needed except ent_acc/done_cnt (done by k1 block 0).
// ---------------------------------------------------------------------------

// Kernel 1: quarter-split stats + Gram partials. 256 blocks (i = b>>2 gram
// row, qd = b&3 -> rows [qd*512, qd*512+512)). All 256 CUs active, 32
// iterations/thread instead of the old 64-block/128-iteration version.
__global__ __launch_bounds__(1024) void stats_gram_kernel(const float* __restrict__ A,
                                                          float* __restrict__ qsums,
                                                          float* __restrict__ qsums2,
                                                          float* __restrict__ gram4,
                                                          float* __restrict__ ent_acc,
                                                          int* __restrict__ done_cnt) {
    int b = blockIdx.x;
    int i = b >> 2, qd = b & 3;
    int tid = threadIdx.x;
    int j = tid & 63, bg = tid >> 6;          // 16 b-groups

    const float* __restrict__ Aq = A + (qd * 512) * R_SZ;
    float g = 0.f, sj = 0.f, s2j = 0.f;
#pragma unroll 4
    for (int t = bg; t < 512; t += 16) {
        float ai = Aq[t * R_SZ + i];          // wave-uniform broadcast
        float aj = Aq[t * R_SZ + j];          // coalesced 256B/wave
        g = fmaf(ai, aj, g);
        sj += aj;
        s2j = fmaf(aj, aj, s2j);
    }

    __shared__ float gred[16][64], sred[16][64], s2red[16][64];
    gred[bg][j] = g; sred[bg][j] = sj; s2red[bg][j] = s2j;
    __syncthreads();
    if (tid < 64) {
        float G = 0.f, S = 0.f, S2 = 0.f;
#pragma unroll
        for (int t = 0; t < 16; ++t) { G += gred[t][j]; S += sred[t][j]; S2 += s2red[t][j]; }
        gram4[b * 64 + j] = G;                // quarter-partial of gram row i
        if (i == 0) {                         // one writer set per quarter
            qsums[qd * 64 + j]  = S;
            qsums2[qd * 64 + j] = S2;
        }
    }
    if (b == 0 && tid == 64) { *ent_acc = 0.f; *done_cnt = 0; }
}

// ---------------------------------------------------------------------------
// Kernel 2: pairwise KDE straight from A (no U buffer). Prologue derives
// h / k0 / lscale from the quarter sums (~0.2us); samples are scaled on the
// fly with one v_mul per load. QT=8, 8-deep register prefetch pipeline,
// 256 blocks x 1024 thr (1 block/CU). Tail: last block assembles the Gram
// quarters into the covariance penalty and emits the scalar loss.
// ---------------------------------------------------------------------------
__global__ __launch_bounds__(1024) void kde_kernel(const float* __restrict__ A,
                                                   const float* __restrict__ qsums,
                                                   const float* __restrict__ qsums2,
                                                   const float* __restrict__ gram4,
                                                   float* __restrict__ ent_acc,
                                                   int* __restrict__ done_cnt,
                                                   float* __restrict__ out) {
    int tid = threadIdx.x;
    int r = tid & 63, sg = tid >> 6;

    // ---- prologue: bandwidth per receptor from quarter sums ----
    __shared__ float k0s[64], lscs[64], sums_s[64];
    if (tid < 64) {
        float S  = qsums[tid]  + qsums[64 + tid]  + qsums[128 + tid]  + qsums[192 + tid];
        float S2 = qsums2[tid] + qsums2[64 + tid] + qsums2[128 + tid] + qsums2[192 + tid];
        float m = S * (1.f / (float)B_SZ);
        float var = (S2 - S * m) * (1.f / (float)(B_SZ - 1));   // ddof=1
        var = fmaxf(var, 0.f);
        float h = fmaxf(1.06f * sqrtf(var) * B_POW_NEG02, 1e-4f);
        k0s[tid]  = sqrtf(0.5f * LOG2E) / h;  // exp2(-(k*d)^2) = exp(-0.5(d/h)^2)
        lscs[tid] = 1.0f / ((float)B_SZ * h * SQRT_2PI);
        sums_s[tid] = S;
    }
    __syncthreads();
    float k0 = k0s[r];

    int q0 = blockIdx.x * QT;
    f32x2 uq01 = { A[(q0 + 0) * R_SZ + r] * k0, A[(q0 + 1) * R_SZ + r] * k0 };
    f32x2 uq23 = { A[(q0 + 2) * R_SZ + r] * k0, A[(q0 + 3) * R_SZ + r] * k0 };
    f32x2 uq45 = { A[(q0 + 4) * R_SZ + r] * k0, A[(q0 + 5) * R_SZ + r] * k0 };
    f32x2 uq67 = { A[(q0 + 6) * R_SZ + r] * k0, A[(q0 + 7) * R_SZ + r] * k0 };
    f32x2 c01 = { 0.f, 0.f }, c23 = { 0.f, 0.f };
    f32x2 c45 = { 0.f, 0.f }, c67 = { 0.f, 0.f };

#define KDE_BODY(usv)                                                          \
    {                                                                          \
        f32x2 uss = { (usv), (usv) };                                          \
        f32x2 d01 = uq01 - uss, d23 = uq23 - uss;                              \
        f32x2 d45 = uq45 - uss, d67 = uq67 - uss;                              \
        f32x2 n01 = -d01 * d01, n23 = -d23 * d23;                              \
        f32x2 n45 = -d45 * d45, n67 = -d67 * d67;                              \
        f32x2 e01 = { __ocml_native_exp2_f32(n01.x), __ocml_native_exp2_f32(n01.y) }; \
        f32x2 e23 = { __ocml_native_exp2_f32(n23.x), __ocml_native_exp2_f32(n23.y) }; \
        f32x2 e45 = { __ocml_native_exp2_f32(n45.x), __ocml_native_exp2_f32(n45.y) }; \
        f32x2 e67 = { __ocml_native_exp2_f32(n67.x), __ocml_native_exp2_f32(n67.y) }; \
        c01 += e01; c23 += e23; c45 += e45; c67 += e67;                        \
    }

    // wave sg consumes s = sg + 16k, k = 0..127; element stride 16*64 = 1024
    const float* __restrict__ Ap = A + sg * R_SZ + r;
    float p[8];
#pragma unroll
    for (int j = 0; j < 8; ++j) p[j] = Ap[j * 1024];   // prologue: 8 in flight

    int li = 8 * 1024;
#pragma unroll 1
    for (int k = 0; k < 15; ++k) {                     // 15 x 8 = 120 consumed
#pragma unroll
        for (int j = 0; j < 8; ++j) {
            float us = p[j] * k0;                      // on-the-fly prescale
            p[j] = Ap[li + j * 1024];                  // prefetch k+8 group
            KDE_BODY(us);
        }
        li += 8 * 1024;
    }
#pragma unroll
    for (int j = 0; j < 8; ++j) { float us = p[j] * k0; KDE_BODY(us); }

#undef KDE_BODY

    // cross-wave reduction of the 8 query-row densities (32 KB LDS)
    __shared__ float red[16][QT][64];
    red[sg][0][r] = c01.x; red[sg][1][r] = c01.y;
    red[sg][2][r] = c23.x; red[sg][3][r] = c23.y;
    red[sg][4][r] = c45.x; red[sg][5][r] = c45.y;
    red[sg][6][r] = c67.x; red[sg][7][r] = c67.y;
    __syncthreads();
    __shared__ float wred[QT];
    if (sg < QT) {                             // wave sg owns query row sg
        float S = 0.f;
#pragma unroll
        for (int t = 0; t < 16; ++t) S += red[t][sg][r];
        float v = __logf(fmaf(S, lscs[r], 1e-8f));
        for (int off = 32; off > 0; off >>= 1) v += __shfl_down(v, off, 64);
        if (r == 0) wred[sg] = v;
    }
    __syncthreads();
    __shared__ int lastflag;
    if (tid == 0) {
        float p2 = 0.f;
#pragma unroll
        for (int t = 0; t < QT; ++t) p2 += wred[t];
        p2 *= (1.0f / ((float)B_SZ * (float)R_SZ));
        atomicAdd(ent_acc, p2);                // once per block
        __threadfence();
        int prev = atomicAdd(done_cnt, 1);
        lastflag = (prev == KDE_BLOCKS - 1);
    }
    __syncthreads();
    if (lastflag) {                            // block-uniform: full fold here
        __threadfence();
        float v = 0.f;
#pragma unroll
        for (int c = tid; c < 4096; c += 1024) {
            int ii = c >> 6, jj = c & 63;      // ii wave-uniform, jj = lane
            const float* gp = gram4 + ii * 256 + jj;
            float G = gp[0] + gp[64] + gp[128] + gp[192];
            float mi = sums_s[ii] * (1.f / (float)B_SZ);
            float mj = sums_s[jj] * (1.f / (float)B_SZ);
            float cov = (G - (float)B_SZ * mi * mj) * (1.f / (float)(B_SZ - 1));
            if (ii != jj) v = fmaf(cov, cov, v);
        }
        for (int off = 32; off > 0; off >>= 1) v += __shfl_down(v, off, 64);
        __shared__ float wsum[16];
        if (r == 0) wsum[sg] = v;
        __syncthreads();
        if (tid == 0) {
            float C = 0.f;
#pragma unroll
            for (int t = 0; t < 16; ++t) C += wsum[t];
            float ent = __hip_atomic_load(ent_acc, __ATOMIC_ACQUIRE,
                                          __HIP_MEMORY_SCOPE_AGENT);
            out[0] = ent + C;                  // COV_WEIGHT = 1.0
        }
    }
}

extern "C" void kernel_launch(void* const* d_in, const int* in_sizes, int n_in,
                              void* d_out, int out_size, void* d_ws, size_t ws_size,
                              hipStream_t stream) {
    const float* A = (const float*)d_in[0];
    float* out = (float*)d_out;

    float* wsf = (float*)d_ws;
    float* qsums   = wsf;                // 256
    float* qsums2  = wsf + 256;          // 256
    float* ent_acc = wsf + 640;          // isolated cache line
    int*   done_cnt = (int*)(wsf + 672);
    float* gram4   = wsf + 1024;         // 64 rows x 4 quarters x 64

    stats_gram_kernel<<<256, 1024, 0, stream>>>(A, qsums, qsums2, gram4,
                                                ent_acc, done_cnt);
    kde_kernel<<<KDE_BLOCKS, 1024, 0, stream>>>(A, qsums, qsums2, gram4,
                                                ent_acc, done_cnt, out);
}